// Round 11
// baseline (517.584 us; speedup 1.0000x reference)
//
#include <hip/hip_runtime.h>
#include <hip/hip_bf16.h>

// Problem constants
#define NB 32     // batch
#define NL 2048   // seq len
#define ND 1024   // DQ = DK = NH*DH
#define NHH 16    // heads
#define NDH 64    // head dim

typedef __bf16 bf16;
typedef __attribute__((ext_vector_type(4))) __bf16 bf16x4;
typedef __attribute__((ext_vector_type(8))) __bf16 bf16x8;
typedef __attribute__((ext_vector_type(4))) float f32x4;

#define SBAR __builtin_amdgcn_s_barrier()
#define WAIT_LGKM0 asm volatile("s_waitcnt lgkmcnt(0)" ::: "memory")

// row swizzle on 16B granules (rows 0..7 per tile)
#define SWZ(r) (((r) & 7) << 4)

__device__ __forceinline__ float dot4(float4 a, float4 b) {
  return a.x * b.x + a.y * b.y + a.z * b.z + a.w * b.w;
}

__device__ __forceinline__ bf16x4 cvt4(f32x4 f) {
  bf16x4 v;
  v[0] = (bf16)f[0]; v[1] = (bf16)f[1]; v[2] = (bf16)f[2]; v[3] = (bf16)f[3];
  return v;
}

// ---------------------------------------------------------------------------
// K1: qs[b][o] = q[b] . Wq[o] + bq[o]      grid=1024, block=256
// ---------------------------------------------------------------------------
__global__ __launch_bounds__(256) void qs_kernel(
    const float* __restrict__ q, const float* __restrict__ Wq,
    const float* __restrict__ bq, float* __restrict__ qs) {
  int o = blockIdx.x;
  int lane = threadIdx.x & 63;
  int wv = threadIdx.x >> 6;
  const float4* wrow = reinterpret_cast<const float4*>(Wq + (size_t)o * ND) + lane * 4;
  float4 w0 = wrow[0], w1 = wrow[1], w2 = wrow[2], w3 = wrow[3];
#pragma unroll
  for (int bb = 0; bb < 8; ++bb) {
    int b = wv * 8 + bb;
    const float4* qr = reinterpret_cast<const float4*>(q + (size_t)b * ND) + lane * 4;
    float s = dot4(qr[0], w0) + dot4(qr[1], w1) + dot4(qr[2], w2) + dot4(qr[3], w3);
#pragma unroll
    for (int off = 32; off > 0; off >>= 1) s += __shfl_down(s, off, 64);
    if (lane == 0) qs[(size_t)b * ND + o] = s + bq[o];
  }
}

// ---------------------------------------------------------------------------
// K2: qtb[b][n][i] = bf16( sum_d Wk[n*64+d][i] * qs[b][n*64+d] )
// grid = 16n x 4ic x 4bg = 256 blocks, block=256. Output BF16 (fused's A).
// ---------------------------------------------------------------------------
__global__ __launch_bounds__(256) void qt_kernel(
    const float* __restrict__ Wk, const float* __restrict__ qs,
    bf16* __restrict__ qtb) {
  int n  = blockIdx.x >> 4;
  int ic = (blockIdx.x >> 2) & 3;
  int bg = blockIdx.x & 3;
  int i = ic * 256 + threadIdx.x;
  __shared__ float s_qs[8][64];
  for (int t = threadIdx.x; t < 512; t += 256) {
    int b = t >> 6, d = t & 63;
    s_qs[b][d] = qs[(size_t)(bg * 8 + b) * ND + n * NDH + d];
  }
  __syncthreads();
  float acc[8];
#pragma unroll
  for (int b = 0; b < 8; ++b) acc[b] = 0.f;
  for (int d = 0; d < 64; ++d) {
    float w = Wk[((size_t)(n * NDH + d)) * ND + i];
#pragma unroll
    for (int b = 0; b < 8; ++b) acc[b] += w * s_qs[b][d];
  }
#pragma unroll
  for (int b = 0; b < 8; ++b)
    qtb[((size_t)((bg * 8 + b) * NHH + n)) * ND + i] = (bf16)acc[b];
}

// ---------------------------------------------------------------------------
// K2b: qb[b*16+n] = qs[b][n*64+:] . bk[n*64+:]    grid=2, block=256
// ---------------------------------------------------------------------------
__global__ __launch_bounds__(256) void qb_kernel(
    const float* __restrict__ qs, const float* __restrict__ bk,
    float* __restrict__ qb) {
  int t = blockIdx.x * 256 + threadIdx.x;
  if (t >= 512) return;
  int b = t >> 4, n = t & 15;
  float s = 0.f;
  for (int d = 0; d < 64; ++d)
    s += qs[(size_t)b * ND + n * NDH + d] * bk[n * NDH + d];
  qb[t] = s;
}

// ---------------------------------------------------------------------------
// K3 (FUSED v7): occupancy-first. grid = 32b x nsl (32 or 16) blocks of 256
// threads (4 waves). Tiles of 8 l; kb dbuf 2x16KB; LDS ~39KB; VGPR<=128 ->
// 4 blocks/CU when nsl=32. A-fragments re-read from bf16 qtb (L1-resident,
// 32KB/block) instead of held in VGPRs. T14: next-tile loads issued at tile
// start, ds_write after phase B into the other buffer; raw barriers (no
// vmcnt drain). 3 barriers/tile.
// ---------------------------------------------------------------------------
__global__ __launch_bounds__(256, 4) void fused_kernel(
    const float* __restrict__ kin, const bf16* __restrict__ qtb,
    const float* __restrict__ qb, float* __restrict__ attn,
    float* __restrict__ ctxp, int slbits) {
  int bx = blockIdx.x;
  int b  = bx >> slbits;
  int sl = bx & ((1 << slbits) - 1);
  int ntiles = 256 >> slbits;         // tiles of 8 l
  int lblk = NL >> slbits;            // l-rows per block
  int tid = threadIdx.x, lane = tid & 63, wv = tid >> 6;
  int kg = lane >> 4, ln16 = lane & 15;

  __shared__ __align__(16) char  kb[2][8 * 2048];   // 2 x 16KB bf16 (8l x 1024i)
  __shared__ __align__(16) float pbuf[4][16][20];   // [wave][l(16)][n]
  __shared__ __align__(16) float sP[8][20];         // [l][n]

  // reduce personals (tid<128): l = tid&7, n = tid>>3
  int rl = tid & 7, rn = tid >> 3;
  float qbv = (tid < 128) ? qb[b * NHH + rn] : 0.f;

  // phase-B personals: wave wv owns heads n = wv*4..+3; lane ig covers
  // i-chunks {ig*8..+7} and {512+ig*8..+7}
  int ig = lane;
  f32x4 ctxa[16];
#pragma unroll
  for (int r = 0; r < 16; ++r) ctxa[r] = (f32x4){0.f, 0.f, 0.f, 0.f};

  // stage mapping: row srow = tid>>5 (8 rows), col scol = tid&31
  int srow = tid >> 5, scol = tid & 31;
  const char* ksrc =
      (const char*)(kin + ((size_t)(b * NL + sl * lblk)) * ND);

  const bf16* qrow = qtb + ((size_t)(b * NHH + ln16)) * ND;

  // prologue: stage tile 0 -> kb[0]
  {
#pragma unroll
    for (int m = 0; m < 8; ++m) {
      f32x4 f = *reinterpret_cast<const f32x4*>(
          ksrc + (size_t)srow * 4096 + scol * 16 + m * 512);
      int byte = srow * 2048 + ((scol * 8 + m * 256) ^ SWZ(srow));
      *reinterpret_cast<bf16x4*>(kb[0] + byte) = cvt4(f);
    }
  }
  WAIT_LGKM0;
  SBAR;

  for (int t = 0; t < ntiles; ++t) {
    int cur = t & 1;
    const char* kbc = kb[cur];

    // 1. issue next tile's global loads (in flight across whole tile)
    f32x4 ld0, ld1, ld2, ld3, ld4, ld5, ld6, ld7;
    if (t < ntiles - 1) {
      const char* src = ksrc + (size_t)(t + 1) * 8 * 4096 + srow * 4096 + scol * 16;
      ld0 = *reinterpret_cast<const f32x4*>(src);
      ld1 = *reinterpret_cast<const f32x4*>(src + 512);
      ld2 = *reinterpret_cast<const f32x4*>(src + 1024);
      ld3 = *reinterpret_cast<const f32x4*>(src + 1536);
      ld4 = *reinterpret_cast<const f32x4*>(src + 2048);
      ld5 = *reinterpret_cast<const f32x4*>(src + 2560);
      ld6 = *reinterpret_cast<const f32x4*>(src + 3072);
      ld7 = *reinterpret_cast<const f32x4*>(src + 3584);
    }

    // 2. phase A: partial logits; wave covers kc = wv*256 .. +255.
    //    A-frags from qtb (L1-hot); B from kb rows (l = ln16&7 remap).
    f32x4 acc = {0.f, 0.f, 0.f, 0.f};
#pragma unroll
    for (int mm = 0; mm < 8; ++mm) {
      int kc = wv * 256 + mm * 32 + kg * 8;
      bf16x8 af = *reinterpret_cast<const bf16x8*>(qrow + kc);
      int byteB = (ln16 & 7) * 2048 + ((kc * 2) ^ SWZ(ln16));
      bf16x8 bfr = *reinterpret_cast<const bf16x8*>(kbc + byteB);
      acc = __builtin_amdgcn_mfma_f32_16x16x32_bf16(af, bfr, acc, 0, 0, 0);
    }
    *reinterpret_cast<f32x4*>(&pbuf[wv][ln16][kg * 4]) = acc;
    WAIT_LGKM0;
    SBAR;

    // 3. reduce partials + exp -> sP + attn (unnormalized)
    if (tid < 128) {
      float s = pbuf[0][rl][rn] + pbuf[1][rl][rn] +
                pbuf[2][rl][rn] + pbuf[3][rl][rn];
      float p = __expf((s + qbv) * 0.125f);
      sP[rl][rn] = p;
      attn[((size_t)(rn * NB + b)) * NL + sl * lblk + t * 8 + rl] = p;
    }
    WAIT_LGKM0;
    SBAR;

    // 4. phase B: ctxa += p[l][wv*4..+3] * k[l][i-chunks]
#pragma unroll
    for (int l = 0; l < 8; ++l) {
      int rowb = l * 2048;
      bf16x8 kva = *reinterpret_cast<const bf16x8*>(
          kbc + rowb + ((ig * 16) ^ SWZ(l)));
      bf16x8 kvb = *reinterpret_cast<const bf16x8*>(
          kbc + rowb + ((ig * 16 + 1024) ^ SWZ(l)));
      f32x4 pv = *reinterpret_cast<const f32x4*>(&sP[l][wv * 4]);
      f32x4 ka0, ka1, kb0, kb1;
      ka0[0] = (float)kva[0]; ka0[1] = (float)kva[1];
      ka0[2] = (float)kva[2]; ka0[3] = (float)kva[3];
      ka1[0] = (float)kva[4]; ka1[1] = (float)kva[5];
      ka1[2] = (float)kva[6]; ka1[3] = (float)kva[7];
      kb0[0] = (float)kvb[0]; kb0[1] = (float)kvb[1];
      kb0[2] = (float)kvb[2]; kb0[3] = (float)kvb[3];
      kb1[0] = (float)kvb[4]; kb1[1] = (float)kvb[5];
      kb1[2] = (float)kvb[6]; kb1[3] = (float)kvb[7];
#pragma unroll
      for (int j = 0; j < 4; ++j) {
        ctxa[j * 4 + 0] += pv[j] * ka0;
        ctxa[j * 4 + 1] += pv[j] * ka1;
        ctxa[j * 4 + 2] += pv[j] * kb0;
        ctxa[j * 4 + 3] += pv[j] * kb1;
      }
    }

    // 5. stage-write next tile into the OTHER buffer (no extra barrier:
    //    previous reads of that buffer ended two barriers ago)
    if (t < ntiles - 1) {
      char* dst = kb[cur ^ 1];
      int base = srow * 2048;
#define STM(R, M)                                                          \
      *reinterpret_cast<bf16x4*>(dst + base + ((scol * 8 + (M) * 256) ^    \
                                               SWZ(srow))) = cvt4(R);
      STM(ld0, 0) STM(ld1, 1) STM(ld2, 2) STM(ld3, 3)
      STM(ld4, 4) STM(ld5, 5) STM(ld6, 6) STM(ld7, 7)
#undef STM
    }
    WAIT_LGKM0;
    SBAR;
  }

  // epilogue: store slab (disjoint (wv-heads, ig-chunks) -> no combine)
#pragma unroll
  for (int j = 0; j < 4; ++j) {
    float* dst =
        ctxp + (((size_t)sl * NB + b) * NHH + wv * 4 + j) * ND;
    *reinterpret_cast<f32x4*>(dst + ig * 8)       = ctxa[j * 4 + 0];
    *reinterpret_cast<f32x4*>(dst + ig * 8 + 4)   = ctxa[j * 4 + 1];
    *reinterpret_cast<f32x4*>(dst + 512 + ig * 8)     = ctxa[j * 4 + 2];
    *reinterpret_cast<f32x4*>(dst + 512 + ig * 8 + 4) = ctxa[j * 4 + 3];
  }
}

// ---------------------------------------------------------------------------
// K4: normalize attn rows (divide by row-sum), write invS. grid=512, block=256
// ---------------------------------------------------------------------------
__global__ __launch_bounds__(256) void norm_kernel(float* __restrict__ attn,
                                                   float* __restrict__ invS) {
  int row = blockIdx.x;
  float* p = attn + (size_t)row * NL;
  int tid = threadIdx.x;
  int lane = tid & 63, wv = tid >> 6;
  float v[8];
  float s = 0.f;
#pragma unroll
  for (int j = 0; j < 8; ++j) {
    v[j] = p[tid + j * 256];
    s += v[j];
  }
#pragma unroll
  for (int off = 32; off > 0; off >>= 1) s += __shfl_down(s, off, 64);
  __shared__ float ss[4];
  if (lane == 0) ss[wv] = s;
  __syncthreads();
  float inv = 1.f / (ss[0] + ss[1] + ss[2] + ss[3]);
  if (tid == 0) invS[row] = inv;
#pragma unroll
  for (int j = 0; j < 8; ++j) p[tid + j * 256] = v[j] * inv;
}

// ---------------------------------------------------------------------------
// K5: ctx = sum_sl ctxp[sl]  (unnormalized). grid=512, block=256
// ---------------------------------------------------------------------------
__global__ __launch_bounds__(256) void reduce_kernel(
    const float* __restrict__ ctxp, float* __restrict__ ctx, int nsl) {
  size_t e4 = ((size_t)blockIdx.x * 256 + threadIdx.x) * 4;
  f32x4 s = *reinterpret_cast<const f32x4*>(ctxp + e4);
#pragma unroll 4
  for (int ls = 1; ls < nsl; ++ls)
    s += *reinterpret_cast<const f32x4*>(ctxp + (size_t)ls * NB * NHH * ND + e4);
  *reinterpret_cast<f32x4*>(ctx + e4) = s;
}

// ---------------------------------------------------------------------------
// K6: out[b][o] = (Wv[o].ctx[b][n]) * invS[n*32+b] + bv[o]   grid=1024
// ---------------------------------------------------------------------------
__global__ __launch_bounds__(256) void out_kernel(
    const float* __restrict__ Wv, const float* __restrict__ bv,
    const float* __restrict__ ctx, const float* __restrict__ invS,
    float* __restrict__ out) {
  int o = blockIdx.x;
  int n = o >> 6;
  int lane = threadIdx.x & 63;
  int wv = threadIdx.x >> 6;
  const float4* wrow = reinterpret_cast<const float4*>(Wv + (size_t)o * ND) + lane * 4;
  float4 w0 = wrow[0], w1 = wrow[1], w2 = wrow[2], w3 = wrow[3];
#pragma unroll
  for (int bb = 0; bb < 8; ++bb) {
    int b = wv * 8 + bb;
    const float4* cr =
        reinterpret_cast<const float4*>(ctx + ((size_t)(b * NHH + n)) * ND) + lane * 4;
    float s = dot4(cr[0], w0) + dot4(cr[1], w1) + dot4(cr[2], w2) + dot4(cr[3], w3);
#pragma unroll
    for (int off = 32; off > 0; off >>= 1) s += __shfl_down(s, off, 64);
    if (lane == 0) out[(size_t)b * ND + o] = s * invS[n * NB + b] + bv[o];
  }
}

// ---------------------------------------------------------------------------
extern "C" void kernel_launch(void* const* d_in, const int* in_sizes, int n_in,
                              void* d_out, int out_size, void* d_ws, size_t ws_size,
                              hipStream_t stream) {
  const float* q  = (const float*)d_in[0];
  const float* k  = (const float*)d_in[1];
  const float* Wq = (const float*)d_in[2];
  const float* bq = (const float*)d_in[3];
  const float* Wk = (const float*)d_in[4];
  const float* bk = (const float*)d_in[5];
  const float* Wv = (const float*)d_in[6];
  const float* bv = (const float*)d_in[7];

  float* out  = (float*)d_out;         // [32][1024]
  float* attn = out + NB * ND;         // [512][2048]  (n-major)

  // ws floats: qs 32768 | qtb (bf16, 262144 float-slots) | qb 512 |
  //            invS 512 | ctx 524288 | ctxp nsl*524288
  float* ws   = (float*)d_ws;
  float* qs   = ws;
  bf16*  qtb  = (bf16*)(ws + 32768);
  float* qb   = ws + 32768 + 262144;
  float* invS = qb + 512;
  float* ctx  = invS + 512;
  float* ctxp = ctx + 524288;

  size_t base_floats = 32768 + 262144 + 512 + 512 + 524288;
  int slbits = (ws_size / 4 >= base_floats + (size_t)32 * 524288) ? 5 : 4;
  int nsl = 1 << slbits;

  qs_kernel<<<1024, 256, 0, stream>>>(q, Wq, bq, qs);
  qt_kernel<<<256, 256, 0, stream>>>(Wk, qs, qtb);
  qb_kernel<<<2, 256, 0, stream>>>(qs, bk, qb);
  fused_kernel<<<32 * nsl, 256, 0, stream>>>(k, qtb, qb, attn, ctxp, slbits);
  norm_kernel<<<512, 256, 0, stream>>>(attn, invS);
  reduce_kernel<<<512, 256, 0, stream>>>(ctxp, ctx, nsl);
  out_kernel<<<1024, 256, 0, stream>>>(Wv, bv, ctx, invS, out);
}

// Round 12
// 143.634 us; speedup vs baseline: 3.6035x; 3.6035x over previous
//
#include <hip/hip_runtime.h>
#include <hip/hip_bf16.h>

// Problem constants
#define NB 32     // batch
#define NL 2048   // seq len
#define ND 1024   // DQ = DK = NH*DH
#define NHH 16    // heads
#define NDH 64    // head dim

typedef __bf16 bf16;
typedef __attribute__((ext_vector_type(4))) __bf16 bf16x4;
typedef __attribute__((ext_vector_type(8))) __bf16 bf16x8;
typedef __attribute__((ext_vector_type(4))) float f32x4;

#define SBAR __builtin_amdgcn_s_barrier()
#define WAIT_LGKM0 asm volatile("s_waitcnt lgkmcnt(0)" ::: "memory")

// two-level row swizzle on 16B/8B granules (proven R6/R10), rows 0..15
#define SWZ(r) ((((r) & 7) << 4) ^ (((r) & 8) << 2))

__device__ __forceinline__ float dot4(float4 a, float4 b) {
  return a.x * b.x + a.y * b.y + a.z * b.z + a.w * b.w;
}

__device__ __forceinline__ bf16x4 cvt4(f32x4 f) {
  bf16x4 v;
  v[0] = (bf16)f[0]; v[1] = (bf16)f[1]; v[2] = (bf16)f[2]; v[3] = (bf16)f[3];
  return v;
}

// ---------------------------------------------------------------------------
// K1: qs[b][o] = q[b] . Wq[o] + bq[o]      grid=1024, block=256
// ---------------------------------------------------------------------------
__global__ __launch_bounds__(256) void qs_kernel(
    const float* __restrict__ q, const float* __restrict__ Wq,
    const float* __restrict__ bq, float* __restrict__ qs) {
  int o = blockIdx.x;
  int lane = threadIdx.x & 63;
  int wv = threadIdx.x >> 6;
  const float4* wrow = reinterpret_cast<const float4*>(Wq + (size_t)o * ND) + lane * 4;
  float4 w0 = wrow[0], w1 = wrow[1], w2 = wrow[2], w3 = wrow[3];
#pragma unroll
  for (int bb = 0; bb < 8; ++bb) {
    int b = wv * 8 + bb;
    const float4* qr = reinterpret_cast<const float4*>(q + (size_t)b * ND) + lane * 4;
    float s = dot4(qr[0], w0) + dot4(qr[1], w1) + dot4(qr[2], w2) + dot4(qr[3], w3);
#pragma unroll
    for (int off = 32; off > 0; off >>= 1) s += __shfl_down(s, off, 64);
    if (lane == 0) qs[(size_t)b * ND + o] = s + bq[o];
  }
}

// ---------------------------------------------------------------------------
// K2: qtb[b][n][i] = bf16( sum_d Wk[n*64+d][i] * qs[b][n*64+d] )
// grid = 16n x 4ic x 4bg = 256 blocks, block=256 (strided s_qs stage).
// ---------------------------------------------------------------------------
__global__ __launch_bounds__(256) void qt_kernel(
    const float* __restrict__ Wk, const float* __restrict__ qs,
    bf16* __restrict__ qtb) {
  int n  = blockIdx.x >> 4;
  int ic = (blockIdx.x >> 2) & 3;
  int bg = blockIdx.x & 3;
  int i = ic * 256 + threadIdx.x;
  __shared__ float s_qs[8][64];
  for (int t = threadIdx.x; t < 512; t += 256) {
    int b = t >> 6, d = t & 63;
    s_qs[b][d] = qs[(size_t)(bg * 8 + b) * ND + n * NDH + d];
  }
  __syncthreads();
  float acc[8];
#pragma unroll
  for (int b = 0; b < 8; ++b) acc[b] = 0.f;
  for (int d = 0; d < 64; ++d) {
    float w = Wk[((size_t)(n * NDH + d)) * ND + i];
#pragma unroll
    for (int b = 0; b < 8; ++b) acc[b] += w * s_qs[b][d];
  }
#pragma unroll
  for (int b = 0; b < 8; ++b)
    qtb[((size_t)((bg * 8 + b) * NHH + n)) * ND + i] = (bf16)acc[b];
}

// ---------------------------------------------------------------------------
// K2b: qb[b*16+n] = qs[b][n*64+:] . bk[n*64+:]    grid=2, block=256
// ---------------------------------------------------------------------------
__global__ __launch_bounds__(256) void qb_kernel(
    const float* __restrict__ qs, const float* __restrict__ bk,
    float* __restrict__ qb) {
  int t = blockIdx.x * 256 + threadIdx.x;
  if (t >= 512) return;
  int b = t >> 4, n = t & 15;
  float s = 0.f;
  for (int d = 0; d < 64; ++d)
    s += qs[(size_t)b * ND + n * NDH + d] * bk[n * NDH + d];
  qb[t] = s;
}

// ---------------------------------------------------------------------------
// K3 (FUSED v8): occupancy via low VGPR + single LDS buffer.
// grid = 32b x 16sl = 512 blocks, 512 threads (8 waves).
// LDS: kb 1x32KB + pbuf 10.25KB + sP 1.25KB ~= 44KB -> 3 blocks/CU.
// VGPR: no held loads, no afrag regs (A-frags re-read from bf16 qtb, L1-hot);
// peak ~78 regs; __launch_bounds__(512,6) caps ~84 -> 24 waves/CU.
// Per 16-l tile: stage(inline) -> bar -> phaseA MFMA -> bar -> reduce+exp
// -> bar -> phaseB (low-DS VALU FMA) -> bar. Cross-block desync overlaps
// HBM/LDS/VALU pipes. k read from HBM exactly once.
// ---------------------------------------------------------------------------
__global__ __launch_bounds__(512, 6) void fused_kernel(
    const float* __restrict__ kin, const bf16* __restrict__ qtb,
    const float* __restrict__ qb, float* __restrict__ attn,
    float* __restrict__ ctxp) {
  int bx = blockIdx.x;
  int b  = bx >> 4;
  int sl = bx & 15;
  int tid = threadIdx.x, lane = tid & 63, wv = tid >> 6;
  int kg = lane >> 4, ln16 = lane & 15;

  __shared__ __align__(16) char  kb[16 * 2048];     // 32 KB bf16 (16l x 1024i)
  __shared__ __align__(16) float pbuf[8][16][20];   // [wave][l][n]
  __shared__ __align__(16) float sP[16][20];        // [l][n]

  // reduce-phase personals (tid<256): (l = tid&15, n = tid>>4)
  int rn = tid >> 4, rl = tid & 15;
  float qbv = (tid < 256) ? qb[b * NHH + rn] : 0.f;

  // phase-B personals: nb = tid>>7 (4 heads each), ig = tid&127 (8 i each)
  int nb = tid >> 7, ig = tid & 127;
  f32x4 ctxa[8];
#pragma unroll
  for (int r = 0; r < 8; ++r) ctxa[r] = (f32x4){0.f, 0.f, 0.f, 0.f};

  // stage mapping: row sr = tid>>5 (16 rows), granule sc = tid&31
  int sr = tid >> 5, sc = tid & 31;
  const float* ksrc = kin + ((size_t)(b * NL + sl * 128 + sr)) * ND + sc * 4;

  // A-fragment source row (qtb, bf16): head = ln16
  const bf16* qrow = qtb + ((size_t)(b * NHH + ln16)) * ND;

  for (int t = 0; t < 8; ++t) {
    // 1. stage tile t -> kb (kb free: phase B of t-1 ended before a barrier)
    {
      const float* src = ksrc + (size_t)t * 16 * ND;
#pragma unroll
      for (int m = 0; m < 8; ++m) {
        f32x4 f = *reinterpret_cast<const f32x4*>(src + m * 128);
        int byte = sr * 2048 + ((sc * 8 + m * 256) ^ SWZ(sr));
        *reinterpret_cast<bf16x4*>(kb + byte) = cvt4(f);
      }
    }
    WAIT_LGKM0;
    SBAR;

    // 2. phase A: partial logits; wave covers kc = wv*128 .. +127.
    //    A-frags re-read from qtb (L1-hot, 16B per MFMA).
    f32x4 acc = {0.f, 0.f, 0.f, 0.f};
#pragma unroll
    for (int mm = 0; mm < 4; ++mm) {
      int kc = wv * 128 + mm * 32 + kg * 8;
      bf16x8 af = *reinterpret_cast<const bf16x8*>(qrow + kc);
      int byteB = ln16 * 2048 + ((kc * 2) ^ SWZ(ln16));
      bf16x8 bfr = *reinterpret_cast<const bf16x8*>(kb + byteB);
      acc = __builtin_amdgcn_mfma_f32_16x16x32_bf16(af, bfr, acc, 0, 0, 0);
    }
    *reinterpret_cast<f32x4*>(&pbuf[wv][ln16][kg * 4]) = acc;
    WAIT_LGKM0;
    SBAR;

    // 3. reduce partials + exp -> sP + attn (unnormalized)
    if (tid < 256) {
      float s = 0.f;
#pragma unroll
      for (int w = 0; w < 8; ++w) s += pbuf[w][rl][rn];
      float p = __expf((s + qbv) * 0.125f);
      sP[rl][rn] = p;
      attn[((size_t)(rn * NB + b)) * NL + sl * 128 + t * 16 + rl] = p;
    }
    WAIT_LGKM0;
    SBAR;

    // 4. phase B: ctxa += p[l][nb*4..+3] * k[l][ig*8..+7]
#pragma unroll 4
    for (int l = 0; l < 16; ++l) {
      bf16x8 kv = *reinterpret_cast<const bf16x8*>(
          kb + l * 2048 + ((ig * 16) ^ SWZ(l)));
      f32x4 pv = *reinterpret_cast<const f32x4*>(&sP[l][nb * 4]);
      f32x4 k0, k1;
      k0[0] = (float)kv[0]; k0[1] = (float)kv[1];
      k0[2] = (float)kv[2]; k0[3] = (float)kv[3];
      k1[0] = (float)kv[4]; k1[1] = (float)kv[5];
      k1[2] = (float)kv[6]; k1[3] = (float)kv[7];
#pragma unroll
      for (int n = 0; n < 4; ++n) {
        ctxa[n * 2]     += pv[n] * k0;
        ctxa[n * 2 + 1] += pv[n] * k1;
      }
    }
    WAIT_LGKM0;
    SBAR;  // kb free for next stage; sP safe (rewritten 2 barriers later)
  }

  // epilogue: store slab (disjoint (nb, ig) -> no combine)
#pragma unroll
  for (int n = 0; n < 4; ++n) {
    float* dst = ctxp + (((size_t)sl * NB + b) * NHH + nb * 4 + n) * ND + ig * 8;
    *reinterpret_cast<f32x4*>(dst)     = ctxa[n * 2];
    *reinterpret_cast<f32x4*>(dst + 4) = ctxa[n * 2 + 1];
  }
}

// ---------------------------------------------------------------------------
// K4: normalize attn rows (divide by row-sum), write invS. grid=512, block=256
// ---------------------------------------------------------------------------
__global__ __launch_bounds__(256) void norm_kernel(float* __restrict__ attn,
                                                   float* __restrict__ invS) {
  int row = blockIdx.x;
  float* p = attn + (size_t)row * NL;
  int tid = threadIdx.x;
  int lane = tid & 63, wv = tid >> 6;
  float v[8];
  float s = 0.f;
#pragma unroll
  for (int j = 0; j < 8; ++j) {
    v[j] = p[tid + j * 256];
    s += v[j];
  }
#pragma unroll
  for (int off = 32; off > 0; off >>= 1) s += __shfl_down(s, off, 64);
  __shared__ float ss[4];
  if (lane == 0) ss[wv] = s;
  __syncthreads();
  float inv = 1.f / (ss[0] + ss[1] + ss[2] + ss[3]);
  if (tid == 0) invS[row] = inv;
#pragma unroll
  for (int j = 0; j < 8; ++j) p[tid + j * 256] = v[j] * inv;
}

// ---------------------------------------------------------------------------
// K5: ctx = sum_sl ctxp[sl]  (unnormalized). grid=512, block=256, f32x4 each
// ---------------------------------------------------------------------------
__global__ __launch_bounds__(256) void reduce_kernel(
    const float* __restrict__ ctxp, float* __restrict__ ctx) {
  size_t e4 = ((size_t)blockIdx.x * 256 + threadIdx.x) * 4;
  f32x4 s = *reinterpret_cast<const f32x4*>(ctxp + e4);
#pragma unroll
  for (int sl = 1; sl < 16; ++sl)
    s += *reinterpret_cast<const f32x4*>(ctxp + (size_t)sl * NB * NHH * ND + e4);
  *reinterpret_cast<f32x4*>(ctx + e4) = s;
}

// ---------------------------------------------------------------------------
// K6: out[b][o] = (Wv[o].ctx[b][n]) * invS[n*32+b] + bv[o]   grid=1024
// ---------------------------------------------------------------------------
__global__ __launch_bounds__(256) void out_kernel(
    const float* __restrict__ Wv, const float* __restrict__ bv,
    const float* __restrict__ ctx, const float* __restrict__ invS,
    float* __restrict__ out) {
  int o = blockIdx.x;
  int n = o >> 6;
  int lane = threadIdx.x & 63;
  int wv = threadIdx.x >> 6;
  const float4* wrow = reinterpret_cast<const float4*>(Wv + (size_t)o * ND) + lane * 4;
  float4 w0 = wrow[0], w1 = wrow[1], w2 = wrow[2], w3 = wrow[3];
#pragma unroll
  for (int bb = 0; bb < 8; ++bb) {
    int b = wv * 8 + bb;
    const float4* cr =
        reinterpret_cast<const float4*>(ctx + ((size_t)(b * NHH + n)) * ND) + lane * 4;
    float s = dot4(cr[0], w0) + dot4(cr[1], w1) + dot4(cr[2], w2) + dot4(cr[3], w3);
#pragma unroll
    for (int off = 32; off > 0; off >>= 1) s += __shfl_down(s, off, 64);
    if (lane == 0) out[(size_t)b * ND + o] = s * invS[n * NB + b] + bv[o];
  }
}

// ---------------------------------------------------------------------------
extern "C" void kernel_launch(void* const* d_in, const int* in_sizes, int n_in,
                              void* d_out, int out_size, void* d_ws, size_t ws_size,
                              hipStream_t stream) {
  const float* q  = (const float*)d_in[0];
  const float* k  = (const float*)d_in[1];
  const float* Wq = (const float*)d_in[2];
  const float* bq = (const float*)d_in[3];
  const float* Wk = (const float*)d_in[4];
  const float* bk = (const float*)d_in[5];
  const float* Wv = (const float*)d_in[6];
  const float* bv = (const float*)d_in[7];

  float* out  = (float*)d_out;         // [32][1024]
  float* attn = out + NB * ND;         // [512][2048]  (n-major)

  // ws floats: qs 32768 | qtb (bf16 -> 262144 float-slots) | qb 512 |
  //            invS 512 | ctx 524288 | ctxp 16*524288
  float* ws   = (float*)d_ws;
  float* qs   = ws;
  bf16*  qtb  = (bf16*)(ws + 32768);
  float* qb   = ws + 32768 + 262144;
  float* invS = qb + 512;
  float* ctx  = invS + 512;
  float* ctxp = ctx + 524288;

  qs_kernel<<<1024, 256, 0, stream>>>(q, Wq, bq, qs);
  qt_kernel<<<256, 256, 0, stream>>>(Wk, qs, qtb);
  qb_kernel<<<2, 256, 0, stream>>>(qs, bk, qb);
  fused_kernel<<<512, 512, 0, stream>>>(k, qtb, qb, attn, ctxp);
  norm_kernel<<<512, 256, 0, stream>>>(attn, invS);
  reduce_kernel<<<512, 256, 0, stream>>>(ctxp, ctx);
  out_kernel<<<1024, 256, 0, stream>>>(Wv, bv, ctx, invS, out);
}